// Round 1
// baseline (4308.933 us; speedup 1.0000x reference)
//
#include <hip/hip_runtime.h>

#define DI __device__ __forceinline__

typedef __attribute__((ext_vector_type(4))) float f32x4;
typedef __attribute__((ext_vector_type(8))) short short8;
typedef unsigned short u16;

DI u16 f2bf(float f) {
  unsigned u = __builtin_bit_cast(unsigned, f);
  u += 0x7fffu + ((u >> 16) & 1u);
  return (u16)(u >> 16);
}
DI float bf2f(u16 h) {
  unsigned u = ((unsigned)h) << 16;
  return __builtin_bit_cast(float, u);
}

// ---------------------------------------------------------------------------
// GEMM: C = epilogue(A[M,K] * B[N,K]^T), A lda=K, B ldb=K (both row-major).
// MODE 0: fp32 out = acc*scale + bias[n]          -> Cp + z*sC + m*N + n
// MODE 1: bf16 out = relu(acc + bias[n])          -> Cp + m*N + n
// MODE 2: bf16 out = acc*scale, QKV head scatter  -> q[(b*16+h)*1024 + t][d]
//         (m = t*2+b, n = h*64+d)
// MODE 3: bf16 out = acc                          -> Cp + z*sC + m*N + n
// MODE 4: bf16 out = acc, attn-out scatter        -> out[(m*2+b)*1024 + h*64+n]
//         (z = b*16+h)
// ---------------------------------------------------------------------------
template <int BM, int BN, bool AF32, bool BF32, int MODE>
__global__ __launch_bounds__(256, 2) void gemm_bt(
    const void* __restrict__ Ap, const void* __restrict__ Bp,
    void* __restrict__ Cp, const float* __restrict__ bias,
    int M, int N, int K, long sA, long sB, long sC, float scale) {
  constexpr int EPT_A = BM * 64 / 256;  // elems per thread for A tile
  constexpr int EPT_B = BN * 64 / 256;
  constexpr int SEG_A = 64 / EPT_A;
  constexpr int SEG_B = 64 / EPT_B;
  constexpr int WM = BM / 2, WN = BN / 2, FM = WM / 16, FN = WN / 16;

  __shared__ char As[BM * 128];
  __shared__ char Bs[BN * 128];

  const int tid = threadIdx.x;
  const int z = blockIdx.z;
  const long bm = (long)blockIdx.y * BM;
  const long bn = (long)blockIdx.x * BN;

  const float* A32 = (const float*)Ap + (AF32 ? z * sA : 0);
  const u16*   A16 = (const u16*)Ap + (AF32 ? 0 : z * sA);
  const float* B32 = (const float*)Bp + (BF32 ? z * sB : 0);
  const u16*   B16 = (const u16*)Bp + (BF32 ? 0 : z * sB);

  float fa[EPT_A]; u16 ha[EPT_A];
  float fb[EPT_B]; u16 hb[EPT_B];

  const int rowA = tid / SEG_A, colA = (tid % SEG_A) * EPT_A;
  const int rowB = tid / SEG_B, colB = (tid % SEG_B) * EPT_B;

  auto loadA = [&](int kt) {
    if constexpr (AF32) {
      const float* p = A32 + (bm + rowA) * (long)K + kt * 64 + colA;
#pragma unroll
      for (int i = 0; i < EPT_A / 4; i++) {
        f32x4 v = *(const f32x4*)(p + i * 4);
        fa[i * 4 + 0] = v[0]; fa[i * 4 + 1] = v[1];
        fa[i * 4 + 2] = v[2]; fa[i * 4 + 3] = v[3];
      }
    } else {
      const u16* p = A16 + (bm + rowA) * (long)K + kt * 64 + colA;
#pragma unroll
      for (int i = 0; i < EPT_A / 8; i++) {
        short8 v = *(const short8*)(p + i * 8);
#pragma unroll
        for (int j = 0; j < 8; j++) ha[i * 8 + j] = (u16)v[j];
      }
    }
  };
  auto loadB = [&](int kt) {
    if constexpr (BF32) {
      const float* p = B32 + (bn + rowB) * (long)K + kt * 64 + colB;
#pragma unroll
      for (int i = 0; i < EPT_B / 4; i++) {
        f32x4 v = *(const f32x4*)(p + i * 4);
        fb[i * 4 + 0] = v[0]; fb[i * 4 + 1] = v[1];
        fb[i * 4 + 2] = v[2]; fb[i * 4 + 3] = v[3];
      }
    } else {
      const u16* p = B16 + (bn + rowB) * (long)K + kt * 64 + colB;
#pragma unroll
      for (int i = 0; i < EPT_B / 8; i++) {
        short8 v = *(const short8*)(p + i * 8);
#pragma unroll
        for (int j = 0; j < 8; j++) hb[i * 8 + j] = (u16)v[j];
      }
    }
  };
  auto writeA = [&]() {
#pragma unroll
    for (int c = 0; c < EPT_A / 8; c++) {
      short8 pk;
      if constexpr (AF32) {
#pragma unroll
        for (int j = 0; j < 8; j++) pk[j] = (short)f2bf(fa[c * 8 + j]);
      } else {
#pragma unroll
        for (int j = 0; j < 8; j++) pk[j] = (short)ha[c * 8 + j];
      }
      int byte = rowA * 128 + (colA + c * 8) * 2;
      byte ^= (rowA & 7) << 4;
      *(short8*)(As + byte) = pk;
    }
  };
  auto writeB = [&]() {
#pragma unroll
    for (int c = 0; c < EPT_B / 8; c++) {
      short8 pk;
      if constexpr (BF32) {
#pragma unroll
        for (int j = 0; j < 8; j++) pk[j] = (short)f2bf(fb[c * 8 + j]);
      } else {
#pragma unroll
        for (int j = 0; j < 8; j++) pk[j] = (short)hb[c * 8 + j];
      }
      int byte = rowB * 128 + (colB + c * 8) * 2;
      byte ^= (rowB & 7) << 4;
      *(short8*)(Bs + byte) = pk;
    }
  };

  const int wid = tid >> 6;
  const int lane = tid & 63;
  const int wm = wid >> 1, wn = wid & 1;
  const int l15 = lane & 15, ks = lane >> 4;

  f32x4 acc[FM][FN];
#pragma unroll
  for (int i = 0; i < FM; i++)
#pragma unroll
    for (int j = 0; j < FN; j++) acc[i][j] = (f32x4){0.f, 0.f, 0.f, 0.f};

  auto compute = [&]() {
#pragma unroll
    for (int kk = 0; kk < 2; kk++) {
      short8 af[FM], bfr[FN];
#pragma unroll
      for (int i = 0; i < FM; i++) {
        int row = wm * WM + i * 16 + l15;
        int byte = row * 128 + kk * 64 + ks * 16;
        byte ^= (row & 7) << 4;
        af[i] = *(const short8*)(As + byte);
      }
#pragma unroll
      for (int j = 0; j < FN; j++) {
        int row = wn * WN + j * 16 + l15;
        int byte = row * 128 + kk * 64 + ks * 16;
        byte ^= (row & 7) << 4;
        bfr[j] = *(const short8*)(Bs + byte);
      }
#pragma unroll
      for (int i = 0; i < FM; i++)
#pragma unroll
        for (int j = 0; j < FN; j++)
          acc[i][j] = __builtin_amdgcn_mfma_f32_16x16x32_bf16(af[i], bfr[j],
                                                              acc[i][j], 0, 0, 0);
    }
  };

  const int NT = K / 64;
  loadA(0); loadB(0);
  writeA(); writeB();
  __syncthreads();
  for (int t = 0; t < NT; ++t) {
    if (t + 1 < NT) { loadA(t + 1); loadB(t + 1); }
    compute();
    __syncthreads();
    if (t + 1 < NT) {
      writeA(); writeB();
    }
    __syncthreads();
  }

  // epilogue
#pragma unroll
  for (int i = 0; i < FM; i++) {
#pragma unroll
    for (int j = 0; j < FN; j++) {
#pragma unroll
      for (int r = 0; r < 4; r++) {
        long m = bm + wm * WM + i * 16 + ks * 4 + r;
        long n = bn + wn * WN + j * 16 + l15;
        float val = acc[i][j][r] * scale;
        if constexpr (MODE == 0) {
          if (bias) val += bias[n];
          ((float*)Cp)[z * sC + m * (long)N + n] = val;
        } else if constexpr (MODE == 1) {
          val += bias[n];
          ((u16*)Cp)[m * (long)N + n] = f2bf(fmaxf(val, 0.f));
        } else if constexpr (MODE == 2) {
          long t_ = m >> 1;
          int b_ = (int)(m & 1), h_ = (int)(n >> 6), d_ = (int)(n & 63);
          ((u16*)Cp)[(((long)(b_ * 16 + h_) * 1024 + t_) << 6) + d_] = f2bf(val);
        } else if constexpr (MODE == 3) {
          ((u16*)Cp)[z * sC + m * (long)N + n] = f2bf(val);
        } else {
          int b_ = z >> 4, h_ = z & 15;
          ((u16*)Cp)[((m * 2 + b_) << 10) + h_ * 64 + (int)n] = f2bf(val);
        }
      }
    }
  }
}

// ---------------------------------------------------------------------------
// V transpose: v [32][1024][64] bf16 -> vt [32][64][1024] bf16
// ---------------------------------------------------------------------------
__global__ __launch_bounds__(256) void transpose_v_k(const u16* __restrict__ v,
                                                     u16* __restrict__ vt) {
  __shared__ u16 tile[64][68];
  const int z = blockIdx.y;
  const int t0 = blockIdx.x * 64;
  const int tid = threadIdx.x;
  const int r = tid >> 2, c0 = (tid & 3) * 16;
  const u16* src = v + ((long)z * 1024 + t0 + r) * 64 + c0;
  short8 v0 = *(const short8*)src;
  short8 v1 = *(const short8*)(src + 8);
#pragma unroll
  for (int j = 0; j < 8; j++) {
    tile[r][c0 + j] = (u16)v0[j];
    tile[r][c0 + 8 + j] = (u16)v1[j];
  }
  __syncthreads();
  short8 o0, o1;
#pragma unroll
  for (int j = 0; j < 8; j++) {
    o0[j] = (short)tile[c0 + j][r];
    o1[j] = (short)tile[c0 + 8 + j][r];
  }
  u16* dst = vt + ((long)z * 64 + r) * 1024 + t0 + c0;
  *(short8*)dst = o0;
  *(short8*)(dst + 8) = o1;
}

// ---------------------------------------------------------------------------
// softmax in-place over bf16 rows of 1024; one wave per row
// ---------------------------------------------------------------------------
__global__ __launch_bounds__(256) void softmax_k(u16* __restrict__ s) {
  const long row = (long)blockIdx.x * 4 + (threadIdx.x >> 6);
  const int lane = threadIdx.x & 63;
  u16* p = s + row * 1024;
  short8 a = *(short8*)(p + lane * 8);
  short8 b = *(short8*)(p + 512 + lane * 8);
  float f[16];
#pragma unroll
  for (int j = 0; j < 8; j++) {
    f[j] = bf2f((u16)a[j]);
    f[8 + j] = bf2f((u16)b[j]);
  }
  float mx = f[0];
#pragma unroll
  for (int j = 1; j < 16; j++) mx = fmaxf(mx, f[j]);
#pragma unroll
  for (int off = 1; off < 64; off <<= 1) mx = fmaxf(mx, __shfl_xor(mx, off));
  float sum = 0.f;
#pragma unroll
  for (int j = 0; j < 16; j++) {
    f[j] = __expf(f[j] - mx);
    sum += f[j];
  }
#pragma unroll
  for (int off = 1; off < 64; off <<= 1) sum += __shfl_xor(sum, off);
  float inv = 1.f / sum;
#pragma unroll
  for (int j = 0; j < 8; j++) {
    a[j] = (short)f2bf(f[j] * inv);
    b[j] = (short)f2bf(f[8 + j] * inv);
  }
  *(short8*)(p + lane * 8) = a;
  *(short8*)(p + 512 + lane * 8) = b;
}

// ---------------------------------------------------------------------------
// out = LN(x (+ r)) * g + b, rows of 1024 fp32, one block per row
// ---------------------------------------------------------------------------
__global__ __launch_bounds__(256) void add_ln_k(const float* __restrict__ x,
                                                const float* __restrict__ r,
                                                const float* __restrict__ g,
                                                const float* __restrict__ b,
                                                float* __restrict__ out) {
  const long row = blockIdx.x;
  const int tid = threadIdx.x;
  f32x4 v = *(const f32x4*)(x + row * 1024 + tid * 4);
  if (r) {
    f32x4 q = *(const f32x4*)(r + row * 1024 + tid * 4);
    v[0] += q[0]; v[1] += q[1]; v[2] += q[2]; v[3] += q[3];
  }
  float s = v[0] + v[1] + v[2] + v[3];
  float s2 = v[0] * v[0] + v[1] * v[1] + v[2] * v[2] + v[3] * v[3];
#pragma unroll
  for (int off = 1; off < 64; off <<= 1) {
    s += __shfl_xor(s, off);
    s2 += __shfl_xor(s2, off);
  }
  __shared__ float ps[8];
  const int wid = tid >> 6, lane = tid & 63;
  if (lane == 0) {
    ps[wid] = s;
    ps[4 + wid] = s2;
  }
  __syncthreads();
  s = ps[0] + ps[1] + ps[2] + ps[3];
  s2 = ps[4] + ps[5] + ps[6] + ps[7];
  float mean = s * (1.f / 1024.f);
  float var = s2 * (1.f / 1024.f) - mean * mean;
  float rstd = rsqrtf(var + 1e-5f);
  f32x4 gg = *(const f32x4*)(g + tid * 4);
  f32x4 bb = *(const f32x4*)(b + tid * 4);
  f32x4 o;
#pragma unroll
  for (int j = 0; j < 4; j++) o[j] = (v[j] - mean) * rstd * gg[j] + bb[j];
  *(f32x4*)(out + row * 1024 + tid * 4) = o;
}

// ---------------------------------------------------------------------------
extern "C" void kernel_launch(void* const* d_in, const int* in_sizes, int n_in,
                              void* d_out, int out_size, void* d_ws,
                              size_t ws_size, hipStream_t stream) {
  const float* src = (const float*)d_in[0];
  const float* tgt = (const float*)d_in[1];
  const float* enc_Wq = (const float*)d_in[2];
  const float* enc_Wk = (const float*)d_in[3];
  const float* enc_Wv = (const float*)d_in[4];
  const float* enc_Wo = (const float*)d_in[5];
  const float* enc_bo = (const float*)d_in[6];
  const float* enc_ln1_g = (const float*)d_in[7];
  const float* enc_ln1_b = (const float*)d_in[8];
  const float* enc_W1 = (const float*)d_in[9];
  const float* enc_b1 = (const float*)d_in[10];
  const float* enc_W2 = (const float*)d_in[11];
  const float* enc_b2 = (const float*)d_in[12];
  const float* enc_ln2_g = (const float*)d_in[13];
  const float* enc_ln2_b = (const float*)d_in[14];
  const float* enc_fn_g = (const float*)d_in[15];
  const float* enc_fn_b = (const float*)d_in[16];
  const float* dec_sWq = (const float*)d_in[17];
  const float* dec_sWk = (const float*)d_in[18];
  const float* dec_sWv = (const float*)d_in[19];
  const float* dec_sWo = (const float*)d_in[20];
  const float* dec_sbo = (const float*)d_in[21];
  const float* dec_ln1_g = (const float*)d_in[22];
  const float* dec_ln1_b = (const float*)d_in[23];
  const float* dec_cWq = (const float*)d_in[24];
  const float* dec_cWk = (const float*)d_in[25];
  const float* dec_cWv = (const float*)d_in[26];
  const float* dec_cWo = (const float*)d_in[27];
  const float* dec_cbo = (const float*)d_in[28];
  const float* dec_ln2_g = (const float*)d_in[29];
  const float* dec_ln2_b = (const float*)d_in[30];
  const float* dec_W1 = (const float*)d_in[31];
  const float* dec_b1 = (const float*)d_in[32];
  const float* dec_W2 = (const float*)d_in[33];
  const float* dec_b2 = (const float*)d_in[34];
  const float* dec_ln3_g = (const float*)d_in[35];
  const float* dec_ln3_b = (const float*)d_in[36];
  const float* dec_fn_g = (const float*)d_in[37];
  const float* dec_fn_b = (const float*)d_in[38];

  char* ws = (char*)d_ws;
  size_t off = 0;
  auto alloc = [&](size_t bytes) {
    void* p = ws + off;
    off += (bytes + 255) & ~(size_t)255;
    return p;
  };
  float* x = (float*)alloc(2048L * 1024 * 4);
  float* y = (float*)alloc(2048L * 1024 * 4);
  float* mem = (float*)alloc(2048L * 1024 * 4);
  float* tmp = (float*)alloc(2048L * 1024 * 4);
  u16* h = (u16*)alloc(2048L * 4096 * 2);
  u16* q = (u16*)alloc(2048L * 1024 * 2);
  u16* kb = (u16*)alloc(2048L * 1024 * 2);
  u16* vb = (u16*)alloc(2048L * 1024 * 2);
  u16* vt = (u16*)alloc(2048L * 1024 * 2);
  u16* ab = (u16*)alloc(2048L * 1024 * 2);
  u16* sc = (u16*)alloc(32L * 1024 * 1024 * 2);

  hipMemcpyAsync(x, src, 2048L * 1024 * 4, hipMemcpyDeviceToDevice, stream);
  hipMemcpyAsync(y, tgt, 2048L * 1024 * 4, hipMemcpyDeviceToDevice, stream);

  auto proj_qkv = [&](const float* in, const float* W, u16* outp, float scl) {
    gemm_bt<128, 128, true, true, 2><<<dim3(8, 16, 1), 256, 0, stream>>>(
        in, W, outp, nullptr, 2048, 1024, 1024, 0, 0, 0, scl);
  };
  auto attn = [&](const float* qin, const float* kvin, const float* Wq,
                  const float* Wk, const float* Wv, const float* Wo,
                  const float* bo, float* outtmp) {
    proj_qkv(qin, Wq, q, 0.125f);
    proj_qkv(kvin, Wk, kb, 1.f);
    proj_qkv(kvin, Wv, vb, 1.f);
    transpose_v_k<<<dim3(16, 32), 256, 0, stream>>>(vb, vt);
    gemm_bt<128, 128, false, false, 3><<<dim3(8, 8, 32), 256, 0, stream>>>(
        q, kb, sc, nullptr, 1024, 1024, 64, 65536, 65536, 1048576, 1.f);
    softmax_k<<<dim3(8192), 256, 0, stream>>>(sc);
    gemm_bt<128, 64, false, false, 4><<<dim3(1, 8, 32), 256, 0, stream>>>(
        sc, vt, ab, nullptr, 1024, 64, 1024, 1048576, 65536, 0, 1.f);
    gemm_bt<128, 128, false, true, 0><<<dim3(8, 16, 1), 256, 0, stream>>>(
        ab, Wo, outtmp, bo, 2048, 1024, 1024, 0, 0, 0, 1.f);
  };
  auto ffn = [&](const float* xin, const float* W1, const float* b1,
                 const float* W2, const float* b2, float* outtmp) {
    gemm_bt<128, 128, true, true, 1><<<dim3(32, 16, 1), 256, 0, stream>>>(
        xin, W1, h, b1, 2048, 4096, 1024, 0, 0, 0, 1.f);
    gemm_bt<128, 128, false, true, 0><<<dim3(8, 16, 1), 256, 0, stream>>>(
        h, W2, outtmp, b2, 2048, 1024, 4096, 0, 0, 0, 1.f);
  };
  auto addln = [&](const float* xin, const float* res, const float* g,
                   const float* b, float* outp) {
    add_ln_k<<<dim3(2048), 256, 0, stream>>>(xin, res, g, b, outp);
  };

  const long DD = 1024L * 1024, Dv = 1024, FFD = 4096L * 1024, FFv = 4096;

  for (int i = 0; i < 4; i++) {
    attn(x, x, enc_Wq + i * DD, enc_Wk + i * DD, enc_Wv + i * DD,
         enc_Wo + i * DD, enc_bo + i * Dv, tmp);
    addln(x, tmp, enc_ln1_g + i * Dv, enc_ln1_b + i * Dv, x);
    ffn(x, enc_W1 + i * FFD, enc_b1 + i * FFv, enc_W2 + i * FFD,
        enc_b2 + i * Dv, tmp);
    addln(x, tmp, enc_ln2_g + i * Dv, enc_ln2_b + i * Dv, x);
  }
  addln(x, nullptr, enc_fn_g, enc_fn_b, mem);

  for (int i = 0; i < 4; i++) {
    attn(y, y, dec_sWq + i * DD, dec_sWk + i * DD, dec_sWv + i * DD,
         dec_sWo + i * DD, dec_sbo + i * Dv, tmp);
    addln(y, tmp, dec_ln1_g + i * Dv, dec_ln1_b + i * Dv, y);
    attn(y, mem, dec_cWq + i * DD, dec_cWk + i * DD, dec_cWv + i * DD,
         dec_cWo + i * DD, dec_cbo + i * Dv, tmp);
    addln(y, tmp, dec_ln2_g + i * Dv, dec_ln2_b + i * Dv, y);
    ffn(y, dec_W1 + i * FFD, dec_b1 + i * FFv, dec_W2 + i * FFD,
        dec_b2 + i * Dv, tmp);
    addln(y, tmp, dec_ln3_g + i * Dv, dec_ln3_b + i * Dv, y);
  }
  addln(y, nullptr, dec_fn_g, dec_fn_b, (float*)d_out);
}

// Round 3
// 2511.283 us; speedup vs baseline: 1.7158x; 1.7158x over previous
//
#include <hip/hip_runtime.h>

#define DI __device__ __forceinline__

typedef __attribute__((ext_vector_type(4))) float f32x4;
typedef __attribute__((ext_vector_type(8))) short short8;
typedef __attribute__((ext_vector_type(4))) short s16x4;
typedef unsigned short u16;

DI u16 f2bf(float f) {
  unsigned u = __builtin_bit_cast(unsigned, f);
  u += 0x7fffu + ((u >> 16) & 1u);
  return (u16)(u >> 16);
}
DI float bf2f(u16 h) {
  unsigned u = ((unsigned)h) << 16;
  return __builtin_bit_cast(float, u);
}

// ---------------------------------------------------------------------------
// GEMM: C = epilogue(A[.,lda] * B[.,ldb]^T), bf16 A, bf16/fp32 B.
// Double-buffered LDS, single barrier per K-step. K-slice offset = z*kz.
// MODE 0: fp32 out = acc (split-K partial)        -> Cp + z*sC + m*N + n
// MODE 1: bf16 out = relu(acc + bias[n])          -> Cp + m*N + n
// MODE 2: QKV fused: z selects {Wq,Wk,Wv},{q,k,v}; bf16 out = acc*scl,
//         head scatter -> out[((b*16+h)*1024 + t)*64 + d]  (m=t*2+b, n=h*64+d)
// MODE 3: bf16 out = acc                          -> Cp + z*sC + m*N + n
// MODE 4: bf16 out = acc, attn-out scatter        -> out[(m*2+b)*1024 + h*64+n]
// ---------------------------------------------------------------------------
template <int BM, int BN, int MODE, bool BF32>
__global__ __launch_bounds__(256, 2) void gemm_bt(
    const void* __restrict__ Ap, const void* __restrict__ Ap2,
    const void* __restrict__ Bp, const void* __restrict__ Bp2,
    const void* __restrict__ Bp3, void* __restrict__ Cp,
    void* __restrict__ Cp2, void* __restrict__ Cp3,
    const float* __restrict__ bias, int N, int lda, int ldb, int kz, int NT,
    long sA, long sB, long sC, float scale) {
  constexpr int EPT_A = BM * 64 / 256;
  constexpr int EPT_B = BN * 64 / 256;
  constexpr int SEG_A = 64 / EPT_A;
  constexpr int SEG_B = 64 / EPT_B;
  constexpr int WM = BM / 2, WN = BN / 2, FM = WM / 16, FN = WN / 16;
  constexpr int TILE = (BM + BN) * 128;

  __shared__ char smem[2 * TILE];

  const int tid = threadIdx.x;
  const int z = blockIdx.z;
  const long bm = (long)blockIdx.y * BM;
  const long bn = (long)blockIdx.x * BN;
  const int kofs = z * kz;

  const void* Asel = (MODE == 2) ? (z == 0 ? Ap : Ap2) : Ap;
  const void* Bsel = (MODE == 2) ? (z == 0 ? Bp : (z == 1 ? Bp2 : Bp3)) : Bp;
  const u16* A16 = (const u16*)Asel + z * sA;
  const u16* B16 = (const u16*)Bsel + z * sB;
  const float* B32 = (const float*)Bsel + z * sB;

  u16 ha[EPT_A];
  float fb32[BF32 ? EPT_B : 1];
  u16 hb[BF32 ? 1 : EPT_B];

  const int rowA = tid / SEG_A, colA = (tid % SEG_A) * EPT_A;
  const int rowB = tid / SEG_B, colB = (tid % SEG_B) * EPT_B;

  auto loadA = [&](int kt) {
    const u16* p = A16 + (bm + rowA) * (long)lda + kofs + kt * 64 + colA;
#pragma unroll
    for (int i = 0; i < EPT_A / 8; i++) {
      short8 v = *(const short8*)(p + i * 8);
#pragma unroll
      for (int j = 0; j < 8; j++) ha[i * 8 + j] = (u16)v[j];
    }
  };
  auto loadB = [&](int kt) {
    if constexpr (BF32) {
      const float* p = B32 + (bn + rowB) * (long)ldb + kofs + kt * 64 + colB;
#pragma unroll
      for (int i = 0; i < EPT_B / 4; i++) {
        f32x4 v = *(const f32x4*)(p + i * 4);
        fb32[i * 4 + 0] = v[0]; fb32[i * 4 + 1] = v[1];
        fb32[i * 4 + 2] = v[2]; fb32[i * 4 + 3] = v[3];
      }
    } else {
      const u16* p = B16 + (bn + rowB) * (long)ldb + kofs + kt * 64 + colB;
#pragma unroll
      for (int i = 0; i < EPT_B / 8; i++) {
        short8 v = *(const short8*)(p + i * 8);
#pragma unroll
        for (int j = 0; j < 8; j++) hb[i * 8 + j] = (u16)v[j];
      }
    }
  };
  auto writeTile = [&](char* buf) {
    char* As = buf;
    char* Bs = buf + BM * 128;
#pragma unroll
    for (int c = 0; c < EPT_A / 8; c++) {
      short8 pk;
#pragma unroll
      for (int j = 0; j < 8; j++) pk[j] = (short)ha[c * 8 + j];
      int byte = rowA * 128 + (colA + c * 8) * 2;
      byte ^= (rowA & 7) << 4;
      *(short8*)(As + byte) = pk;
    }
#pragma unroll
    for (int c = 0; c < EPT_B / 8; c++) {
      short8 pk;
      if constexpr (BF32) {
#pragma unroll
        for (int j = 0; j < 8; j++) pk[j] = (short)f2bf(fb32[c * 8 + j]);
      } else {
#pragma unroll
        for (int j = 0; j < 8; j++) pk[j] = (short)hb[c * 8 + j];
      }
      int byte = rowB * 128 + (colB + c * 8) * 2;
      byte ^= (rowB & 7) << 4;
      *(short8*)(Bs + byte) = pk;
    }
  };

  const int wid = tid >> 6;
  const int lane = tid & 63;
  const int wm = wid >> 1, wn = wid & 1;
  const int l15 = lane & 15, ks = lane >> 4;

  f32x4 acc[FM][FN];
#pragma unroll
  for (int i = 0; i < FM; i++)
#pragma unroll
    for (int j = 0; j < FN; j++) acc[i][j] = (f32x4){0.f, 0.f, 0.f, 0.f};

  auto compute = [&](const char* buf) {
    const char* As = buf;
    const char* Bs = buf + BM * 128;
#pragma unroll
    for (int kk = 0; kk < 2; kk++) {
      short8 af[FM], bfr[FN];
#pragma unroll
      for (int i = 0; i < FM; i++) {
        int row = wm * WM + i * 16 + l15;
        int byte = row * 128 + kk * 64 + ks * 16;
        byte ^= (row & 7) << 4;
        af[i] = *(const short8*)(As + byte);
      }
#pragma unroll
      for (int j = 0; j < FN; j++) {
        int row = wn * WN + j * 16 + l15;
        int byte = row * 128 + kk * 64 + ks * 16;
        byte ^= (row & 7) << 4;
        bfr[j] = *(const short8*)(Bs + byte);
      }
#pragma unroll
      for (int i = 0; i < FM; i++)
#pragma unroll
        for (int j = 0; j < FN; j++)
          acc[i][j] = __builtin_amdgcn_mfma_f32_16x16x32_bf16(af[i], bfr[j],
                                                              acc[i][j], 0, 0, 0);
    }
  };

  loadA(0);
  loadB(0);
  writeTile(smem);
  __syncthreads();
  for (int t = 0; t < NT; ++t) {
    const char* cur = smem + (t & 1) * TILE;
    char* nxt = smem + ((t + 1) & 1) * TILE;
    bool has_next = (t + 1 < NT);
    if (has_next) { loadA(t + 1); loadB(t + 1); }
    compute(cur);
    if (has_next) writeTile(nxt);
    __syncthreads();
  }

  const float scl = (MODE == 2 && z > 0) ? 1.f : scale;
#pragma unroll
  for (int i = 0; i < FM; i++) {
#pragma unroll
    for (int j = 0; j < FN; j++) {
#pragma unroll
      for (int r = 0; r < 4; r++) {
        long m = bm + wm * WM + i * 16 + ks * 4 + r;
        long n = bn + wn * WN + j * 16 + l15;
        float val = acc[i][j][r] * scl;
        if constexpr (MODE == 0) {
          ((float*)Cp)[z * sC + m * (long)N + n] = val;
        } else if constexpr (MODE == 1) {
          val += bias[n];
          ((u16*)Cp)[m * (long)N + n] = f2bf(fmaxf(val, 0.f));
        } else if constexpr (MODE == 2) {
          u16* Cz = (u16*)(z == 0 ? Cp : (z == 1 ? Cp2 : Cp3));
          long t_ = m >> 1;
          int b_ = (int)(m & 1), h_ = (int)(n >> 6), d_ = (int)(n & 63);
          Cz[(((long)(b_ * 16 + h_) * 1024 + t_) << 6) + d_] = f2bf(val);
        } else if constexpr (MODE == 3) {
          ((u16*)Cp)[z * sC + m * (long)N + n] = f2bf(val);
        } else {
          int b_ = z >> 4, h_ = z & 15;
          ((u16*)Cp)[((m * 2 + b_) << 10) + h_ * 64 + (int)n] = f2bf(val);
        }
      }
    }
  }
}

// ---------------------------------------------------------------------------
// V transpose: v [32][1024][64] bf16 -> vt [32][64][1024] bf16
// ---------------------------------------------------------------------------
__global__ __launch_bounds__(256) void transpose_v_k(const u16* __restrict__ v,
                                                     u16* __restrict__ vt) {
  __shared__ u16 tile[64][68];
  const int z = blockIdx.y;
  const int t0 = blockIdx.x * 64;
  const int tid = threadIdx.x;
  const int r = tid >> 2, c0 = (tid & 3) * 16;
  const u16* src = v + ((long)z * 1024 + t0 + r) * 64 + c0;
  short8 v0 = *(const short8*)src;
  short8 v1 = *(const short8*)(src + 8);
#pragma unroll
  for (int j = 0; j < 8; j++) {
    tile[r][c0 + j] = (u16)v0[j];
    tile[r][c0 + 8 + j] = (u16)v1[j];
  }
  __syncthreads();
  short8 o0, o1;
#pragma unroll
  for (int j = 0; j < 8; j++) {
    o0[j] = (short)tile[c0 + j][r];
    o1[j] = (short)tile[c0 + 8 + j][r];
  }
  u16* dst = vt + ((long)z * 64 + r) * 1024 + t0 + c0;
  *(short8*)dst = o0;
  *(short8*)(dst + 8) = o1;
}

// ---------------------------------------------------------------------------
// softmax in-place over bf16 rows of 1024; one wave per row
// ---------------------------------------------------------------------------
__global__ __launch_bounds__(256) void softmax_k(u16* __restrict__ s) {
  const long row = (long)blockIdx.x * 4 + (threadIdx.x >> 6);
  const int lane = threadIdx.x & 63;
  u16* p = s + row * 1024;
  short8 a = *(short8*)(p + lane * 8);
  short8 b = *(short8*)(p + 512 + lane * 8);
  float f[16];
#pragma unroll
  for (int j = 0; j < 8; j++) {
    f[j] = bf2f((u16)a[j]);
    f[8 + j] = bf2f((u16)b[j]);
  }
  float mx = f[0];
#pragma unroll
  for (int j = 1; j < 16; j++) mx = fmaxf(mx, f[j]);
#pragma unroll
  for (int off = 1; off < 64; off <<= 1) mx = fmaxf(mx, __shfl_xor(mx, off));
  float sum = 0.f;
#pragma unroll
  for (int j = 0; j < 16; j++) {
    f[j] = __expf(f[j] - mx);
    sum += f[j];
  }
#pragma unroll
  for (int off = 1; off < 64; off <<= 1) sum += __shfl_xor(sum, off);
  float inv = 1.f / sum;
#pragma unroll
  for (int j = 0; j < 8; j++) {
    a[j] = (short)f2bf(f[j] * inv);
    b[j] = (short)f2bf(f[8 + j] * inv);
  }
  *(short8*)(p + lane * 8) = a;
  *(short8*)(p + 512 + lane * 8) = b;
}

// ---------------------------------------------------------------------------
// out = LN(x + sum(parts) + cb) * g + b ; writes fp32 out and optional bf16
// ---------------------------------------------------------------------------
template <int NP>
__global__ __launch_bounds__(256) void add_ln_k(
    const float* __restrict__ x, const float* __restrict__ parts,
    const float* __restrict__ cb, const float* __restrict__ g,
    const float* __restrict__ b, float* __restrict__ out,
    u16* __restrict__ outh) {
  const long row = blockIdx.x;
  const int tid = threadIdx.x;
  const long base = row * 1024 + tid * 4;
  f32x4 v = *(const f32x4*)(x + base);
#pragma unroll
  for (int p = 0; p < NP; p++) {
    f32x4 q = *(const f32x4*)(parts + (long)p * 2048 * 1024 + base);
    v[0] += q[0]; v[1] += q[1]; v[2] += q[2]; v[3] += q[3];
  }
  if (cb) {
    f32x4 q = *(const f32x4*)(cb + tid * 4);
    v[0] += q[0]; v[1] += q[1]; v[2] += q[2]; v[3] += q[3];
  }
  float s = v[0] + v[1] + v[2] + v[3];
  float s2 = v[0] * v[0] + v[1] * v[1] + v[2] * v[2] + v[3] * v[3];
#pragma unroll
  for (int off = 1; off < 64; off <<= 1) {
    s += __shfl_xor(s, off);
    s2 += __shfl_xor(s2, off);
  }
  __shared__ float ps[8];
  const int wid = tid >> 6, lane = tid & 63;
  if (lane == 0) {
    ps[wid] = s;
    ps[4 + wid] = s2;
  }
  __syncthreads();
  s = ps[0] + ps[1] + ps[2] + ps[3];
  s2 = ps[4] + ps[5] + ps[6] + ps[7];
  float mean = s * (1.f / 1024.f);
  float var = s2 * (1.f / 1024.f) - mean * mean;
  float rstd = rsqrtf(var + 1e-5f);
  f32x4 gg = *(const f32x4*)(g + tid * 4);
  f32x4 bb = *(const f32x4*)(b + tid * 4);
  f32x4 o;
#pragma unroll
  for (int j = 0; j < 4; j++) o[j] = (v[j] - mean) * rstd * gg[j] + bb[j];
  *(f32x4*)(out + base) = o;
  if (outh) {
    s16x4 hh;
#pragma unroll
    for (int j = 0; j < 4; j++) hh[j] = (short)f2bf(o[j]);
    *(s16x4*)(outh + base) = hh;
  }
}

// fp32 -> (fp32 copy, bf16 copy)
__global__ __launch_bounds__(256) void cast_k(const float* __restrict__ in,
                                              float* __restrict__ o32,
                                              u16* __restrict__ o16) {
  const long i = ((long)blockIdx.x * 256 + threadIdx.x) * 4;
  f32x4 v = *(const f32x4*)(in + i);
  *(f32x4*)(o32 + i) = v;
  s16x4 hh;
#pragma unroll
  for (int j = 0; j < 4; j++) hh[j] = (short)f2bf(v[j]);
  *(s16x4*)(o16 + i) = hh;
}

// ---------------------------------------------------------------------------
extern "C" void kernel_launch(void* const* d_in, const int* in_sizes, int n_in,
                              void* d_out, int out_size, void* d_ws,
                              size_t ws_size, hipStream_t stream) {
  const float* src = (const float*)d_in[0];
  const float* tgt = (const float*)d_in[1];
  const float* enc_Wq = (const float*)d_in[2];
  const float* enc_Wk = (const float*)d_in[3];
  const float* enc_Wv = (const float*)d_in[4];
  const float* enc_Wo = (const float*)d_in[5];
  const float* enc_bo = (const float*)d_in[6];
  const float* enc_ln1_g = (const float*)d_in[7];
  const float* enc_ln1_b = (const float*)d_in[8];
  const float* enc_W1 = (const float*)d_in[9];
  const float* enc_b1 = (const float*)d_in[10];
  const float* enc_W2 = (const float*)d_in[11];
  const float* enc_b2 = (const float*)d_in[12];
  const float* enc_ln2_g = (const float*)d_in[13];
  const float* enc_ln2_b = (const float*)d_in[14];
  const float* enc_fn_g = (const float*)d_in[15];
  const float* enc_fn_b = (const float*)d_in[16];
  const float* dec_sWq = (const float*)d_in[17];
  const float* dec_sWk = (const float*)d_in[18];
  const float* dec_sWv = (const float*)d_in[19];
  const float* dec_sWo = (const float*)d_in[20];
  const float* dec_sbo = (const float*)d_in[21];
  const float* dec_ln1_g = (const float*)d_in[22];
  const float* dec_ln1_b = (const float*)d_in[23];
  const float* dec_cWq = (const float*)d_in[24];
  const float* dec_cWk = (const float*)d_in[25];
  const float* dec_cWv = (const float*)d_in[26];
  const float* dec_cWo = (const float*)d_in[27];
  const float* dec_cbo = (const float*)d_in[28];
  const float* dec_ln2_g = (const float*)d_in[29];
  const float* dec_ln2_b = (const float*)d_in[30];
  const float* dec_W1 = (const float*)d_in[31];
  const float* dec_b1 = (const float*)d_in[32];
  const float* dec_W2 = (const float*)d_in[33];
  const float* dec_b2 = (const float*)d_in[34];
  const float* dec_ln3_g = (const float*)d_in[35];
  const float* dec_ln3_b = (const float*)d_in[36];
  const float* dec_fn_g = (const float*)d_in[37];
  const float* dec_fn_b = (const float*)d_in[38];

  char* ws = (char*)d_ws;
  size_t off = 0;
  auto alloc = [&](size_t bytes) {
    void* p = ws + off;
    off += (bytes + 255) & ~(size_t)255;
    return p;
  };
  float* xf = (float*)alloc(2048L * 1024 * 4);   // encoder x, then decoder y
  float* mem = (float*)alloc(2048L * 1024 * 4);
  u16* xh = (u16*)alloc(2048L * 1024 * 2);
  u16* memh = (u16*)alloc(2048L * 1024 * 2);
  u16* h = (u16*)alloc(2048L * 4096 * 2);
  u16* q = (u16*)alloc(2048L * 1024 * 2);
  u16* kb = (u16*)alloc(2048L * 1024 * 2);
  u16* vb = (u16*)alloc(2048L * 1024 * 2);
  u16* vt = (u16*)alloc(2048L * 1024 * 2);
  u16* ab = (u16*)alloc(2048L * 1024 * 2);
  u16* sc = (u16*)alloc(32L * 1024 * 1024 * 2);  // scores; partials alias this
  float* parts = (float*)sc;

  const long sP = 2048L * 1024;

  auto attn = [&](const u16* qin, const u16* kvin, const float* Wq,
                  const float* Wk, const float* Wv, const float* Wo) {
    // fused QKV projection (z: 0=Q,1=K,2=V)
    gemm_bt<128, 128, 2, true><<<dim3(8, 16, 3), 256, 0, stream>>>(
        qin, kvin, Wq, Wk, Wv, q, kb, vb, nullptr,
        1024, 1024, 1024, 0, 16, 0, 0, 0, 0.125f);
    transpose_v_k<<<dim3(16, 32), 256, 0, stream>>>(vb, vt);
    // QK^T per head
    gemm_bt<128, 128, 3, false><<<dim3(8, 8, 32), 256, 0, stream>>>(
        q, nullptr, kb, nullptr, nullptr, sc, nullptr, nullptr, nullptr,
        1024, 64, 64, 0, 1, 65536, 65536, 1048576, 1.f);
    softmax_k<<<dim3(8192), 256, 0, stream>>>(sc);
    // PV per head
    gemm_bt<128, 64, 4, false><<<dim3(1, 8, 32), 256, 0, stream>>>(
        sc, nullptr, vt, nullptr, nullptr, ab, nullptr, nullptr, nullptr,
        64, 1024, 1024, 0, 16, 1048576, 65536, 0, 1.f);
    // O projection, split-K=2 -> fp32 partials
    gemm_bt<128, 128, 0, true><<<dim3(8, 16, 2), 256, 0, stream>>>(
        ab, nullptr, Wo, nullptr, nullptr, parts, nullptr, nullptr, nullptr,
        1024, 1024, 1024, 512, 8, 0, 0, sP, 1.f);
  };
  auto ffn = [&](const u16* xin, const float* W1, const float* b1,
                 const float* W2) {
    gemm_bt<128, 128, 1, true><<<dim3(32, 16, 1), 256, 0, stream>>>(
        xin, nullptr, W1, nullptr, nullptr, h, nullptr, nullptr, b1,
        4096, 1024, 1024, 0, 16, 0, 0, 0, 1.f);
    // FFN2 split-K=4 -> fp32 partials
    gemm_bt<128, 128, 0, true><<<dim3(8, 16, 4), 256, 0, stream>>>(
        h, nullptr, W2, nullptr, nullptr, parts, nullptr, nullptr, nullptr,
        1024, 4096, 4096, 1024, 16, 0, 0, sP, 1.f);
  };

  const long DD = 1024L * 1024, Dv = 1024, FFD = 4096L * 1024, FFv = 4096;

  cast_k<<<dim3(2048), 256, 0, stream>>>(src, xf, xh);
  for (int i = 0; i < 4; i++) {
    attn(xh, xh, enc_Wq + i * DD, enc_Wk + i * DD, enc_Wv + i * DD,
         enc_Wo + i * DD);
    add_ln_k<2><<<dim3(2048), 256, 0, stream>>>(
        xf, parts, enc_bo + i * Dv, enc_ln1_g + i * Dv, enc_ln1_b + i * Dv,
        xf, xh);
    ffn(xh, enc_W1 + i * FFD, enc_b1 + i * FFv, enc_W2 + i * FFD);
    add_ln_k<4><<<dim3(2048), 256, 0, stream>>>(
        xf, parts, enc_b2 + i * Dv, enc_ln2_g + i * Dv, enc_ln2_b + i * Dv,
        xf, xh);
  }
  add_ln_k<0><<<dim3(2048), 256, 0, stream>>>(
      xf, nullptr, nullptr, enc_fn_g, enc_fn_b, mem, memh);

  cast_k<<<dim3(2048), 256, 0, stream>>>(tgt, xf, xh);
  for (int i = 0; i < 4; i++) {
    attn(xh, xh, dec_sWq + i * DD, dec_sWk + i * DD, dec_sWv + i * DD,
         dec_sWo + i * DD);
    add_ln_k<2><<<dim3(2048), 256, 0, stream>>>(
        xf, parts, dec_sbo + i * Dv, dec_ln1_g + i * Dv, dec_ln1_b + i * Dv,
        xf, xh);
    attn(xh, memh, dec_cWq + i * DD, dec_cWk + i * DD, dec_cWv + i * DD,
         dec_cWo + i * DD);
    add_ln_k<2><<<dim3(2048), 256, 0, stream>>>(
        xf, parts, dec_cbo + i * Dv, dec_ln2_g + i * Dv, dec_ln2_b + i * Dv,
        xf, xh);
    ffn(xh, dec_W1 + i * FFD, dec_b1 + i * FFv, dec_W2 + i * FFD);
    add_ln_k<4><<<dim3(2048), 256, 0, stream>>>(
        xf, parts, dec_b2 + i * Dv, dec_ln3_g + i * Dv, dec_ln3_b + i * Dv,
        xf, xh);
  }
  add_ln_k<0><<<dim3(2048), 256, 0, stream>>>(
      xf, nullptr, nullptr, dec_fn_g, dec_fn_b, (float*)d_out, nullptr);
}